// Round 1
// baseline (308.838 us; speedup 1.0000x reference)
//
#include <hip/hip_runtime.h>
#include <hip/hip_bf16.h>

typedef _Float16 f16x8 __attribute__((ext_vector_type(8)));
typedef float    f32x4 __attribute__((ext_vector_type(4)));

#define B_SZ 512
#define T_SZ 2048
#define D_SZ 256
#define TCHUNK 64
#define NCHUNK (T_SZ / TCHUNK)   // 32

// ---------- kernel 1: W_eff[e,k] = sum_d Wa[e,d]*Wi[d,k];  b_eff[e] = Wa[e,:]@(bi+bh) + ba[e]
__global__ __launch_bounds__(256) void prep_kernel(
    const float* __restrict__ Wa, const float* __restrict__ Wi,
    const float* __restrict__ bi, const float* __restrict__ bh,
    const float* __restrict__ ba,
    _Float16* __restrict__ Weff, float* __restrict__ beff)
{
    int e = blockIdx.x;      // output row (256)
    int d = threadIdx.x;     // output col (256)
    float acc = 0.f;
    #pragma unroll 4
    for (int k = 0; k < 256; ++k)
        acc = fmaf(Wa[e*256 + k], Wi[k*256 + d], acc);
    Weff[e*256 + d] = (_Float16)acc;

    __shared__ float red[256];
    red[d] = Wa[e*256 + d] * (bi[d] + bh[d]);
    __syncthreads();
    if (d == 0) {
        float s = ba[e];
        for (int k = 0; k < 256; ++k) s += red[k];
        beff[e] = s;
    }
}

// ---------- kernel 2: fused GEMM(x, W_eff^T) + sigmoid + sum_t attn*x -> ao (B,256)
// one block per batch b; 8 waves, each wave owns 32 output columns.
// x chunk (64 rows x 256 cols) staged fp32->fp16 into XOR-swizzled LDS.
__global__ __launch_bounds__(512) void attn_kernel(
    const float* __restrict__ x,          // (B, T, D)
    const _Float16* __restrict__ Weff,    // (256, 256) row-major [e][k]
    const float* __restrict__ beff,       // (256)
    float* __restrict__ ao)               // (B, 256)
{
    const int b    = blockIdx.x;
    const int tid  = threadIdx.x;
    const int wave = tid >> 6;
    const int lane = tid & 63;
    const int l15  = lane & 15;
    const int lq   = lane >> 4;

    __shared__ _Float16 xs[TCHUNK * 256];   // 32 KB, swizzled: byte ^= (row&7)<<4

    // B fragments for this wave's 32 columns: W_eff[n][k], 8 contiguous k per lane.
    // layout (16x16x32 f16): B lane l holds B[k = 8*(l>>4)+i][n = l&15]; B[k][n] = Weff[n][k]
    f16x8 bfrag[2][8];
    #pragma unroll
    for (int ct = 0; ct < 2; ++ct) {
        int col = wave*32 + ct*16 + l15;
        #pragma unroll
        for (int ks = 0; ks < 8; ++ks) {
            int k0 = ks*32 + lq*8;
            bfrag[ct][ks] = *reinterpret_cast<const f16x8*>(&Weff[col*256 + k0]);
        }
    }
    float bcol[2];
    bcol[0] = beff[wave*32 + l15];
    bcol[1] = beff[wave*32 + 16 + l15];

    const float* xb = x + (size_t)b * T_SZ * D_SZ;

    // staging: thread covers 8 consecutive floats x 4 groups.
    // group i: rows [i*16, i*16+16); row = i*16 + tid/32, col = (tid&31)*8
    const int srow = tid >> 5;           // 0..15
    const int scol = (tid & 31) * 8;

    f32x4 regA[4], regB[4];

    // prologue loads (chunk 0)
    {
        const float* src = xb;
        #pragma unroll
        for (int i = 0; i < 4; ++i) {
            const float* p = src + (size_t)(i*16 + srow) * 256 + scol;
            regA[i] = *reinterpret_cast<const f32x4*>(p);
            regB[i] = *reinterpret_cast<const f32x4*>(p + 4);
        }
    }

    float ao_acc0 = 0.f, ao_acc1 = 0.f;

    for (int c = 0; c < NCHUNK; ++c) {
        __syncthreads();   // previous compute done reading xs
        // convert + write fp16 into swizzled LDS
        #pragma unroll
        for (int i = 0; i < 4; ++i) {
            int row = i*16 + srow;
            f16x8 h;
            h[0] = (_Float16)regA[i][0]; h[1] = (_Float16)regA[i][1];
            h[2] = (_Float16)regA[i][2]; h[3] = (_Float16)regA[i][3];
            h[4] = (_Float16)regB[i][0]; h[5] = (_Float16)regB[i][1];
            h[6] = (_Float16)regB[i][2]; h[7] = (_Float16)regB[i][3];
            int byte = (row*512 + scol*2) ^ ((row & 7) << 4);
            *reinterpret_cast<f16x8*>(reinterpret_cast<char*>(xs) + byte) = h;
        }
        __syncthreads();

        // issue next chunk's global loads early (latency hidden under compute)
        if (c + 1 < NCHUNK) {
            const float* src = xb + (size_t)(c + 1) * (TCHUNK * D_SZ);
            #pragma unroll
            for (int i = 0; i < 4; ++i) {
                const float* p = src + (size_t)(i*16 + srow) * 256 + scol;
                regA[i] = *reinterpret_cast<const f32x4*>(p);
                regB[i] = *reinterpret_cast<const f32x4*>(p + 4);
            }
        }

        // compute: 4 row-tiles x 2 col-tiles, K=256 (8 MFMA steps)
        #pragma unroll
        for (int rt = 0; rt < 4; ++rt) {
            f16x8 afrag[8];
            #pragma unroll
            for (int ks = 0; ks < 8; ++ks) {
                int row = rt*16 + l15;
                int kk  = ks*32 + lq*8;
                int byte = (row*512 + kk*2) ^ ((row & 7) << 4);
                afrag[ks] = *reinterpret_cast<const f16x8*>(
                    reinterpret_cast<const char*>(xs) + byte);
            }
            #pragma unroll
            for (int ct = 0; ct < 2; ++ct) {
                f32x4 acc = {0.f, 0.f, 0.f, 0.f};
                #pragma unroll
                for (int ks = 0; ks < 8; ++ks)
                    acc = __builtin_amdgcn_mfma_f32_16x16x32_f16(
                        afrag[ks], bfrag[ct][ks], acc, 0, 0, 0);
                // C layout: row = (lane>>4)*4 + r, col = lane&15
                float bia = bcol[ct];
                int colb = (wave*32 + ct*16 + l15) * 2;
                #pragma unroll
                for (int r = 0; r < 4; ++r) {
                    int row = rt*16 + lq*4 + r;
                    float s = acc[r] + bia;
                    float attn = __builtin_amdgcn_rcpf(1.f + __expf(-s));
                    int byte = (row*512 + colb) ^ ((row & 7) << 4);
                    float xv = (float)*reinterpret_cast<const _Float16*>(
                        reinterpret_cast<const char*>(xs) + byte);
                    if (ct == 0) ao_acc0 = fmaf(attn, xv, ao_acc0);
                    else         ao_acc1 = fmaf(attn, xv, ao_acc1);
                }
            }
        }
    }

    // reduce over quarter-wave groups (lanes l, l+16, l+32, l+48 share a column)
    {
        float v = ao_acc0;
        v += __shfl_xor(v, 16, 64);
        v += __shfl_xor(v, 32, 64);
        if (lq == 0) ao[b*256 + wave*32 + l15] = v;
        float w = ao_acc1;
        w += __shfl_xor(w, 16, 64);
        w += __shfl_xor(w, 32, 64);
        if (lq == 0) ao[b*256 + wave*32 + 16 + l15] = w;
    }
}

// ---------- kernel 3: LSTM cell (h0=c0=0 => f gate dead, W_hh dead)
__global__ __launch_bounds__(256) void lstm_kernel(
    const float* __restrict__ ao,        // (B, 256)
    const float* __restrict__ Wih,       // (1024, 256)
    const float* __restrict__ bih,       // (1024)
    const float* __restrict__ bhh,       // (1024)
    float* __restrict__ out)             // h (B*256) | h (B*256) | c (B*256)
{
    int b = blockIdx.x;    // 512
    int j = threadIdx.x;   // 256
    __shared__ float a[256];
    a[j] = ao[b*256 + j];
    __syncthreads();

    float gi = bih[j]       + bhh[j];
    float gg = bih[512 + j] + bhh[512 + j];
    float go = bih[768 + j] + bhh[768 + j];
    const float* wi = Wih + (size_t)j * 256;
    const float* wg = Wih + (size_t)(512 + j) * 256;
    const float* wo = Wih + (size_t)(768 + j) * 256;
    #pragma unroll 4
    for (int k = 0; k < 256; k += 4) {
        f32x4 w1 = *reinterpret_cast<const f32x4*>(wi + k);
        f32x4 w2 = *reinterpret_cast<const f32x4*>(wg + k);
        f32x4 w3 = *reinterpret_cast<const f32x4*>(wo + k);
        #pragma unroll
        for (int q = 0; q < 4; ++q) {
            float av = a[k + q];
            gi = fmaf(w1[q], av, gi);
            gg = fmaf(w2[q], av, gg);
            go = fmaf(w3[q], av, go);
        }
    }
    float ig = 1.f / (1.f + __expf(-gi));
    float g  = tanhf(gg);
    float og = 1.f / (1.f + __expf(-go));
    float cc = ig * g;
    float hh = og * tanhf(cc);
    out[          b*256 + j] = hh;
    out[131072 +  b*256 + j] = hh;
    out[262144 +  b*256 + j] = cc;
}

extern "C" void kernel_launch(void* const* d_in, const int* in_sizes, int n_in,
                              void* d_out, int out_size, void* d_ws, size_t ws_size,
                              hipStream_t stream) {
    const float* x    = (const float*)d_in[0];
    const float* Wi   = (const float*)d_in[1];
    const float* bi   = (const float*)d_in[2];
    // d_in[3] = Wh (dead: h0 = 0)
    const float* bh   = (const float*)d_in[4];
    const float* Wa   = (const float*)d_in[5];
    const float* ba   = (const float*)d_in[6];
    const float* W_ih = (const float*)d_in[7];
    const float* b_ih = (const float*)d_in[8];
    // d_in[9] = W_hh (dead: h0 = 0)
    const float* b_hh = (const float*)d_in[10];

    char* ws = (char*)d_ws;
    _Float16* Weff = (_Float16*)ws;                  // 128 KB
    float*    beff = (float*)(ws + 128*1024);        // 1 KB
    float*    ao   = (float*)(ws + 132*1024);        // 512 KB

    prep_kernel<<<256, 256, 0, stream>>>(Wa, Wi, bi, bh, ba, Weff, beff);
    attn_kernel<<<B_SZ, 512, 0, stream>>>(x, Weff, beff, ao);
    lstm_kernel<<<B_SZ, 256, 0, stream>>>(ao, W_ih, b_ih, b_hh, (float*)d_out);
}